// Round 1
// baseline (686.694 us; speedup 1.0000x reference)
//
#include <hip/hip_runtime.h>

#define C_   192
#define N_   32
#define H_   112
#define W_   112
#define W4   28                 // float4s per row
#define PIX  (H_ * W4)          // 3136 float4 outputs per (n,c) plane
#define BLK  256
#define GX   ((PIX + BLK - 1) / BLK)   // 13

// Zero the per-channel sum/sumsq accumulators (ws is poisoned 0xAA each call).
__global__ void zero_acc_kernel(float* __restrict__ acc) {
    for (int i = threadIdx.x; i < 2 * C_; i += blockDim.x) acc[i] = 0.0f;
}

__device__ __forceinline__ void conv_row(const float* __restrict__ row, int j,
                                         float w0, float w1, float w2,
                                         float4& acc) {
    const float4 m = *(const float4*)(row + 4 * j);
    const float l = (j > 0)       ? row[4 * j - 1] : 0.0f;
    const float r = (j < W4 - 1)  ? row[4 * j + 4] : 0.0f;
    acc.x += w0 * l   + w1 * m.x + w2 * m.y;
    acc.y += w0 * m.x + w1 * m.y + w2 * m.z;
    acc.z += w0 * m.y + w1 * m.z + w2 * m.w;
    acc.w += w0 * m.z + w1 * m.w + w2 * r;
}

// 3x3 depthwise conv (no bias — it cancels in BN), zero padding, 4 outputs.
__device__ __forceinline__ float4 conv4(const float* __restrict__ plane,
                                        int h, int j, const float* wc) {
    float4 acc = {0.f, 0.f, 0.f, 0.f};
    if (h > 0)      conv_row(plane + (size_t)(h - 1) * W_, j, wc[0], wc[1], wc[2], acc);
                    conv_row(plane + (size_t)h       * W_, j, wc[3], wc[4], wc[5], acc);
    if (h < H_ - 1) conv_row(plane + (size_t)(h + 1) * W_, j, wc[6], wc[7], wc[8], acc);
    return acc;
}

// Pass 1: per-channel sum and sum-of-squares of the (biasless) conv output.
__global__ __launch_bounds__(BLK) void stats_kernel(const float* __restrict__ in,
                                                    const float* __restrict__ w,
                                                    float* __restrict__ acc) {
    const int nc = blockIdx.y;          // n*C + c
    const int c  = nc % C_;
    const int p  = blockIdx.x * BLK + threadIdx.x;

    float wc[9];
#pragma unroll
    for (int k = 0; k < 9; ++k) wc[k] = w[c * 9 + k];

    float s = 0.0f, ss = 0.0f;
    if (p < PIX) {
        const int h = p / W4, j = p % W4;
        const float* plane = in + (size_t)nc * (H_ * W_);
        const float4 y = conv4(plane, h, j, wc);
        s  = (y.x + y.y) + (y.z + y.w);
        ss = (y.x * y.x + y.y * y.y) + (y.z * y.z + y.w * y.w);
    }

    // wave-64 reduction
#pragma unroll
    for (int off = 32; off > 0; off >>= 1) {
        s  += __shfl_down(s,  off, 64);
        ss += __shfl_down(ss, off, 64);
    }
    __shared__ float ls[BLK / 64], lss[BLK / 64];
    const int lane = threadIdx.x & 63;
    const int wv   = threadIdx.x >> 6;
    if (lane == 0) { ls[wv] = s; lss[wv] = ss; }
    __syncthreads();
    if (threadIdx.x == 0) {
        float S  = 0.f, SS = 0.f;
#pragma unroll
        for (int i = 0; i < BLK / 64; ++i) { S += ls[i]; SS += lss[i]; }
        atomicAdd(&acc[c],      S);
        atomicAdd(&acc[C_ + c], SS);
    }
}

// Pass 1.5: fold stats + gamma/beta into per-channel scale/shift.
__global__ void finalize_kernel(const float* __restrict__ acc,
                                const float* __restrict__ gamma,
                                const float* __restrict__ beta,
                                float* __restrict__ st) {
    const int c = threadIdx.x;
    if (c < C_) {
        const float M    = (float)N_ * (float)H_ * (float)W_;
        const float mean = acc[c] / M;
        float var        = acc[C_ + c] / M - mean * mean;
        var              = fmaxf(var, 0.0f);
        const float sc   = gamma[c] * rsqrtf(var + 1e-5f);
        st[c]       = sc;
        st[C_ + c]  = beta[c] - sc * mean;   // bias b cancels algebraically
    }
}

// Pass 2: recompute conv, apply scale/shift + ReLU6, store.
__global__ __launch_bounds__(BLK) void apply_kernel(const float* __restrict__ in,
                                                    const float* __restrict__ w,
                                                    const float* __restrict__ st,
                                                    float* __restrict__ out) {
    const int nc = blockIdx.y;
    const int c  = nc % C_;
    const int p  = blockIdx.x * BLK + threadIdx.x;
    if (p >= PIX) return;

    float wc[9];
#pragma unroll
    for (int k = 0; k < 9; ++k) wc[k] = w[c * 9 + k];
    const float sc = st[c];
    const float sh = st[C_ + c];

    const int h = p / W4, j = p % W4;
    const float* plane = in + (size_t)nc * (H_ * W_);
    const float4 y = conv4(plane, h, j, wc);

    float4 z;
    z.x = fminf(fmaxf(sc * y.x + sh, 0.0f), 6.0f);
    z.y = fminf(fmaxf(sc * y.y + sh, 0.0f), 6.0f);
    z.z = fminf(fmaxf(sc * y.z + sh, 0.0f), 6.0f);
    z.w = fminf(fmaxf(sc * y.w + sh, 0.0f), 6.0f);

    *(float4*)(out + (size_t)nc * (H_ * W_) + (size_t)p * 4) = z;
}

extern "C" void kernel_launch(void* const* d_in, const int* in_sizes, int n_in,
                              void* d_out, int out_size, void* d_ws, size_t ws_size,
                              hipStream_t stream) {
    const float* in    = (const float*)d_in[0];
    const float* w     = (const float*)d_in[1];
    // d_in[2] = conv bias b: unused — cancels exactly inside training-mode BN.
    const float* gamma = (const float*)d_in[3];
    const float* beta  = (const float*)d_in[4];
    float* out = (float*)d_out;

    float* acc = (float*)d_ws;      // [0, 2C): sum, sumsq
    float* st  = acc + 2 * C_;      // [2C, 4C): scale, shift

    hipLaunchKernelGGL(zero_acc_kernel, dim3(1), dim3(64), 0, stream, acc);

    const dim3 grid(GX, N_ * C_);
    hipLaunchKernelGGL(stats_kernel, grid, dim3(BLK), 0, stream, in, w, acc);
    hipLaunchKernelGGL(finalize_kernel, dim3(1), dim3(C_), 0, stream,
                       acc, gamma, beta, st);
    hipLaunchKernelGGL(apply_kernel, grid, dim3(BLK), 0, stream, in, w, st, out);
}